// Round 6
// baseline (43.913 us; speedup 1.0000x reference)
//
#include <hip/hip_runtime.h>
#include <math.h>

#define NUM_RADIAL 8
#define EMB_DIM    64
#define N_ELEM     83
#define TILE       256   // edges per block; each wave owns 64 edges

typedef float f4 __attribute__((ext_vector_type(4)));

// ---------------------------------------------------------------------------
// Fused single kernel — wave-synchronous, NO __syncthreads, no pre-pass.
// Phase 1 (1 thread = 1 edge): t[8] = emb[Z]·dense_w + b computed inline
//   (dense_w reads are wave-uniform 16B loads -> scalar cache; emb row is
//   16 f4 loads, L2-resident). Y[16] -> LDS stride 17; gated radial cg[8]
//   -> LDS stride 12 (48B rows).
// Phase 2: after wave-local s_waitcnt lgkmcnt(0), the wave streams its own
//   64 edges: out[e][lm][k] = Y[lm]*cg[k]*w[deg(lm)][k]; each thread's
//   (lm,k0,deg) is fixed so w[deg][k0..3] stays in registers. 1KB contiguous
//   per wave-store-instruction. Waves never wait on each other.
// ---------------------------------------------------------------------------
__global__ __launch_bounds__(256) void srb_fused(
    const float* __restrict__ disp,
    const int*   __restrict__ Zj,
    const float* __restrict__ emb,      // 83 x 64
    const float* __restrict__ dw,       // 64 x 8
    const float* __restrict__ db,       // 8
    const float* __restrict__ tw,       // tensor_w, 4 x 8
    float*       __restrict__ out,
    int n_edges)
{
    __shared__ float Yl[TILE * 17];    // stride 17 (odd): conflict-free b32
    __shared__ float CGl[TILE * 12];   // stride 12 floats = 48B, 16B-aligned

    const int tid  = threadIdx.x;
    const int lane = tid & 63;
    const int wv   = tid >> 6;
    const int e    = blockIdx.x * TILE + tid;

    // ---- phase-2 invariants (depend only on lane&31) ----
    const int jj  = lane & 31;         // float4-slot within an edge
    const int lm  = jj >> 1;           // 0..15
    const int k0  = (jj & 1) * 4;      // 0 or 4
    const int l   = (lm > 0) + (lm > 3) + (lm > 8);
    const f4  wl  = *reinterpret_cast<const f4*>(tw + l * NUM_RADIAL + k0);

    if (e < n_edges) {
        const float dx = disp[3 * e + 0];
        const float dy = disp[3 * e + 1];
        const float dz = disp[3 * e + 2];
        const float r2 = dx * dx + dy * dy + dz * dz;
        const float r  = sqrtf(r2);
        const float rinv = (r > 0.0f) ? __builtin_amdgcn_rcpf(r) : 0.0f;
        const float x = dx * rinv, y = dy * rinv, z = dz * rinv;
        const float x2 = x * x, y2 = y * y, z2 = z * z;

        const float s3   = 1.7320508075688772f;   // sqrt(3)
        const float s15  = 3.8729833462074170f;   // sqrt(15)
        const float s5_8 = 0.7905694150420949f;   // sqrt(5/8)
        const float s3_8 = 0.6123724356957945f;   // sqrt(3/8)

        float* Yp = &Yl[tid * 17];
        Yp[0]  = 1.0f;
        Yp[1]  = x;
        Yp[2]  = y;
        Yp[3]  = z;
        Yp[4]  = s3 * x * y;
        Yp[5]  = s3 * y * z;
        Yp[6]  = 0.5f * (3.0f * z2 - 1.0f);
        Yp[7]  = s3 * x * z;
        Yp[8]  = 0.5f * s3 * (x2 - y2);
        Yp[9]  = s5_8 * y * (3.0f * x2 - y2);
        Yp[10] = s15 * x * y * z;
        Yp[11] = s3_8 * y * (5.0f * z2 - 1.0f);
        Yp[12] = 0.5f * z * (5.0f * z2 - 3.0f);
        Yp[13] = s3_8 * x * (5.0f * z2 - 1.0f);
        Yp[14] = 0.5f * s15 * z * (x2 - y2);
        Yp[15] = s5_8 * x * (x2 - 3.0f * y2);

        // ---- t[8] = emb[zidx] . dense_w + dense_b, inline ----
        const int zidx = Zj[e];
        const float* erow = emb + zidx * EMB_DIM;
        f4 tacc0 = { db[0], db[1], db[2], db[3] };   // uniform loads
        f4 tacc1 = { db[4], db[5], db[6], db[7] };
        #pragma unroll
        for (int j4 = 0; j4 < EMB_DIM / 4; ++j4) {
            const f4 ev = *reinterpret_cast<const f4*>(erow + j4 * 4);
            #pragma unroll
            for (int c = 0; c < 4; ++c) {
                const float ej = ((const float*)&ev)[c];
                const int   j  = j4 * 4 + c;
                const f4 w0 = *reinterpret_cast<const f4*>(dw + j * NUM_RADIAL);
                const f4 w1 = *reinterpret_cast<const f4*>(dw + j * NUM_RADIAL + 4);
                tacc0 += ej * w0;                    // uniform-addr dw loads
                tacc1 += ej * w1;
            }
        }
        float t[NUM_RADIAL] = { tacc0.x, tacc0.y, tacc0.z, tacc0.w,
                                tacc1.x, tacc1.y, tacc1.z, tacc1.w };

        const float PI  = 3.14159265358979323846f;
        const float cut = (r < 5.0f) ? (0.5f * (__cosf(PI * r * 0.2f) + 1.0f))
                                     : 0.0f;
        const float pib = PI * r * 0.2f;   // pi*r/CUTOFF

        f4 cga, cgb;
        #pragma unroll
        for (int k = 0; k < NUM_RADIAL; ++k) {
            const float px = pib * (float)(k + 1);
            const float s  = (px != 0.0f) ? (__sinf(px) * __builtin_amdgcn_rcpf(px))
                                          : 1.0f;              // sinc
            const float c  = t[k] * (s * cut);
            const float y0 = c * tw[k];                         // w[0][k]
            const float gate = __builtin_amdgcn_rcpf(1.0f + __expf(-y0));
            const float cg = c * gate;
            if (k < 4) ((float*)&cga)[k] = cg; else ((float*)&cgb)[k - 4] = cg;
        }
        f4* CGp = reinterpret_cast<f4*>(&CGl[tid * 12]);
        CGp[0] = cga;
        CGp[1] = cgb;
    }

    // Wave-local phase boundary: drain this wave's LDS writes, pin ordering.
    __asm__ volatile("s_waitcnt lgkmcnt(0)" ::: "memory");
    __builtin_amdgcn_sched_barrier(0);

    // Phase 2: this wave streams its own 64 edges (2 edges / wave-inst,
    // 1KB contiguous per wave-instruction).
    const int el0 = wv * 64;
    f4* out4 = reinterpret_cast<f4*>(out);
    #pragma unroll 8
    for (int it = 0; it < 32; ++it) {
        const int el   = el0 + it * 2 + (lane >> 5);   // local edge
        const int edge = blockIdx.x * TILE + el;
        if (edge < n_edges) {
            const float yv = Yl[el * 17 + lm];
            const f4 cg = *reinterpret_cast<const f4*>(&CGl[el * 12 + k0]);
            const f4 o  = (yv * cg) * wl;
            out4[edge * 32 + jj] = o;
        }
    }
}

extern "C" void kernel_launch(void* const* d_in, const int* in_sizes, int n_in,
                              void* d_out, int out_size, void* d_ws, size_t ws_size,
                              hipStream_t stream) {
    const float* disp = (const float*)d_in[0];
    const int*   Zj   = (const int*)  d_in[1];
    const float* emb  = (const float*)d_in[2];
    const float* dw   = (const float*)d_in[3];
    const float* db   = (const float*)d_in[4];
    const float* tw   = (const float*)d_in[5];
    float* out = (float*)d_out;

    const int n = in_sizes[1];                        // N_EDGES

    const int nblocks = (n + TILE - 1) / TILE;
    hipLaunchKernelGGL(srb_fused, dim3(nblocks), dim3(256), 0, stream,
                       disp, Zj, emb, dw, db, tw, out, n);
}

// Round 7
// 43.436 us; speedup vs baseline: 1.0110x; 1.0110x over previous
//
#include <hip/hip_runtime.h>
#include <math.h>

#define NUM_RADIAL 8
#define EMB_DIM    64
#define N_ELEM     83
#define TILE       256   // edges per block; each wave owns 64 edges

typedef float f4 __attribute__((ext_vector_type(4)));

// ---------------------------------------------------------------------------
// Single fused kernel.
// Prologue (once per block): build t_table[83][8] = emb @ dense_w + b in LDS.
//   Step A: stage dense_w transposed (dwT[8][64]) in LDS — 2 coalesced reads
//           per thread. Step B: 664 dot-64s spread over 256 threads (~3 per
//           thread, f4 FMAs, emb rows L1/L2-resident). Two barriers, both
//           BEFORE the latency-heavy per-edge section (benign placement).
// Phase 1 (1 thread = 1 edge): Y[16] -> LDS stride 17; gated radial cg[8]
//   (t gathered from LDS t_table) -> LDS stride 12.
// Phase 2 (wave-synchronous, NO block barrier at the 1->2 boundary): after a
//   wave-local s_waitcnt lgkmcnt(0), each wave streams its own 64 edges,
//   1KB contiguous per wave-store-instruction; per-thread (lm,k0,deg) fixed
//   so w[deg][k0..3] stays in registers. Waves never wait on each other.
// ---------------------------------------------------------------------------
__global__ __launch_bounds__(256) void srb_fused(
    const float* __restrict__ disp,
    const int*   __restrict__ Zj,
    const float* __restrict__ emb,      // 83 x 64
    const float* __restrict__ dw,       // 64 x 8
    const float* __restrict__ db,       // 8
    const float* __restrict__ tw,       // tensor_w, 4 x 8
    float*       __restrict__ out,
    int n_edges)
{
    __shared__ float dwT[8][EMB_DIM];      // 2 KB, dense_w transposed
    __shared__ float Tt[N_ELEM * NUM_RADIAL]; // 2.7 KB, per-block t table
    __shared__ float Yl[TILE * 17];        // stride 17 (odd): conflict-free
    __shared__ float CGl[TILE * 12];       // stride 12 floats, 16B-aligned

    const int tid  = threadIdx.x;
    const int lane = tid & 63;
    const int wv   = tid >> 6;
    const int e    = blockIdx.x * TILE + tid;

    // ---- phase-2 invariants (depend only on lane&31) ----
    const int jj  = lane & 31;         // float4-slot within an edge
    const int lm  = jj >> 1;           // 0..15
    const int k0  = (jj & 1) * 4;      // 0 or 4
    const int l   = (lm > 0) + (lm > 3) + (lm > 8);
    const f4  wl  = *reinterpret_cast<const f4*>(tw + l * NUM_RADIAL + k0);

    // ---- prologue A: stage dense_w transposed (coalesced linear reads) ----
    #pragma unroll
    for (int idx = tid; idx < EMB_DIM * NUM_RADIAL; idx += TILE) {
        const int j = idx >> 3;        // 0..63
        const int k = idx & 7;         // 0..7
        dwT[k][j] = dw[idx];           // dw is [64][8] row-major
    }
    __syncthreads();

    // ---- prologue B: t_table[z][k] = emb[z].dwT[k] + db[k] ----
    for (int idx = tid; idx < N_ELEM * NUM_RADIAL; idx += TILE) {
        const int z = idx >> 3;
        const int k = idx & 7;
        const float* er = emb + z * EMB_DIM;
        const float* wr = &dwT[k][0];
        f4 a4 = { 0.0f, 0.0f, 0.0f, 0.0f };
        #pragma unroll
        for (int j4 = 0; j4 < EMB_DIM / 4; ++j4) {
            const f4 ev = *reinterpret_cast<const f4*>(er + 4 * j4);
            const f4 wv2 = *reinterpret_cast<const f4*>(wr + 4 * j4);
            a4 += ev * wv2;
        }
        Tt[idx] = db[k] + a4.x + a4.y + a4.z + a4.w;
    }
    __syncthreads();

    if (e < n_edges) {
        const float dx = disp[3 * e + 0];
        const float dy = disp[3 * e + 1];
        const float dz = disp[3 * e + 2];
        const float r2 = dx * dx + dy * dy + dz * dz;
        const float r  = sqrtf(r2);
        const float rinv = (r > 0.0f) ? __builtin_amdgcn_rcpf(r) : 0.0f;
        const float x = dx * rinv, y = dy * rinv, z = dz * rinv;
        const float x2 = x * x, y2 = y * y, z2 = z * z;

        const float s3   = 1.7320508075688772f;   // sqrt(3)
        const float s15  = 3.8729833462074170f;   // sqrt(15)
        const float s5_8 = 0.7905694150420949f;   // sqrt(5/8)
        const float s3_8 = 0.6123724356957945f;   // sqrt(3/8)

        float* Yp = &Yl[tid * 17];
        Yp[0]  = 1.0f;
        Yp[1]  = x;
        Yp[2]  = y;
        Yp[3]  = z;
        Yp[4]  = s3 * x * y;
        Yp[5]  = s3 * y * z;
        Yp[6]  = 0.5f * (3.0f * z2 - 1.0f);
        Yp[7]  = s3 * x * z;
        Yp[8]  = 0.5f * s3 * (x2 - y2);
        Yp[9]  = s5_8 * y * (3.0f * x2 - y2);
        Yp[10] = s15 * x * y * z;
        Yp[11] = s3_8 * y * (5.0f * z2 - 1.0f);
        Yp[12] = 0.5f * z * (5.0f * z2 - 3.0f);
        Yp[13] = s3_8 * x * (5.0f * z2 - 1.0f);
        Yp[14] = 0.5f * s15 * z * (x2 - y2);
        Yp[15] = s5_8 * x * (x2 - 3.0f * y2);

        const float PI  = 3.14159265358979323846f;
        const float cut = (r < 5.0f) ? (0.5f * (__cosf(PI * r * 0.2f) + 1.0f))
                                     : 0.0f;
        const float pib = PI * r * 0.2f;   // pi*r/CUTOFF

        const int zidx = Zj[e];
        const f4 t0 = *reinterpret_cast<const f4*>(&Tt[zidx * NUM_RADIAL]);
        const f4 t1 = *reinterpret_cast<const f4*>(&Tt[zidx * NUM_RADIAL + 4]);
        float t[NUM_RADIAL] = { t0.x, t0.y, t0.z, t0.w, t1.x, t1.y, t1.z, t1.w };

        f4 cga, cgb;
        #pragma unroll
        for (int k = 0; k < NUM_RADIAL; ++k) {
            const float px = pib * (float)(k + 1);
            const float s  = (px != 0.0f) ? (__sinf(px) * __builtin_amdgcn_rcpf(px))
                                          : 1.0f;              // sinc
            const float c  = t[k] * (s * cut);
            const float y0 = c * tw[k];                         // w[0][k]
            const float gate = __builtin_amdgcn_rcpf(1.0f + __expf(-y0));
            const float cg = c * gate;
            if (k < 4) ((float*)&cga)[k] = cg; else ((float*)&cgb)[k - 4] = cg;
        }
        f4* CGp = reinterpret_cast<f4*>(&CGl[tid * 12]);
        CGp[0] = cga;
        CGp[1] = cgb;
    }

    // Wave-local phase boundary: drain this wave's LDS writes, pin ordering.
    // (No __syncthreads here — waves proceed to their store streams alone.)
    __asm__ volatile("s_waitcnt lgkmcnt(0)" ::: "memory");
    __builtin_amdgcn_sched_barrier(0);

    // Phase 2: this wave streams its own 64 edges (2 edges / wave-inst,
    // 1KB contiguous per wave-instruction).
    const int el0 = wv * 64;
    f4* out4 = reinterpret_cast<f4*>(out);
    #pragma unroll 8
    for (int it = 0; it < 32; ++it) {
        const int el   = el0 + it * 2 + (lane >> 5);   // local edge
        const int edge = blockIdx.x * TILE + el;
        if (edge < n_edges) {
            const float yv = Yl[el * 17 + lm];
            const f4 cg = *reinterpret_cast<const f4*>(&CGl[el * 12 + k0]);
            const f4 o  = (yv * cg) * wl;
            out4[edge * 32 + jj] = o;
        }
    }
}

extern "C" void kernel_launch(void* const* d_in, const int* in_sizes, int n_in,
                              void* d_out, int out_size, void* d_ws, size_t ws_size,
                              hipStream_t stream) {
    const float* disp = (const float*)d_in[0];
    const int*   Zj   = (const int*)  d_in[1];
    const float* emb  = (const float*)d_in[2];
    const float* dw   = (const float*)d_in[3];
    const float* db   = (const float*)d_in[4];
    const float* tw   = (const float*)d_in[5];
    float* out = (float*)d_out;

    const int n = in_sizes[1];                        // N_EDGES

    const int nblocks = (n + TILE - 1) / TILE;
    hipLaunchKernelGGL(srb_fused, dim3(nblocks), dim3(256), 0, stream,
                       disp, Zj, emb, dw, db, tw, out, n);
}

// Round 8
// 42.979 us; speedup vs baseline: 1.0217x; 1.0106x over previous
//
#include <hip/hip_runtime.h>
#include <math.h>

#define NUM_RADIAL 8
#define EMB_DIM    64
#define N_ELEM     83
#define TILE       256     // edges per block-tile; each wave owns 64
#define NBLOCKS    512     // persistent: 2 blocks/CU x 256 CU

typedef float f4 __attribute__((ext_vector_type(4)));

// ---------------------------------------------------------------------------
// Kernel 1: t_table[z][k] = emb_table[z] . dense_w[:,k] + dense_b[k]
// ---------------------------------------------------------------------------
__global__ void srb_precompute_t(const float* __restrict__ emb,
                                 const float* __restrict__ dw,
                                 const float* __restrict__ db,
                                 float* __restrict__ t_table) {
    int idx = blockIdx.x * blockDim.x + threadIdx.x;
    if (idx >= N_ELEM * NUM_RADIAL) return;
    int z = idx >> 3;
    int k = idx & 7;
    float acc = db[k];
    const float* e = emb + z * EMB_DIM;
    #pragma unroll 8
    for (int j = 0; j < EMB_DIM; ++j)
        acc += e[j] * dw[j * NUM_RADIAL + k];
    t_table[idx] = acc;
}

// ---------------------------------------------------------------------------
// Kernel 2: persistent, wave-synchronous, software-pipelined.
// 512 resident blocks grid-stride over ceil(n/256) tiles. Per wave (64 edges
// per tile), double-buffered LDS slices. Steady-state loop body:
//   [issue disp/Zj loads, tile i+2] [t_table gather, tile i+1]
//   [32x1KB store drain of tile i  <- hides all the above latency]
//   [phase-1 compute of tile i+1 into the other buffer] [wave-local lgkmcnt]
// No __syncthreads anywhere; waves never wait on each other.
// LDS 59.4 KB/block -> 2 blocks/CU -> 8 pipelined waves/CU.
// ---------------------------------------------------------------------------
__global__ __launch_bounds__(256, 2) void srb_main(
    const float* __restrict__ disp,
    const int*   __restrict__ Zj,
    const float* __restrict__ tw,       // tensor_w, 4 x 8
    const float* __restrict__ t_table,  // 83 x 8
    float*       __restrict__ out,
    int n_edges, int ntiles)
{
    __shared__ float Yl[2 * 4 * 64 * 17];   // 34816 B, stride 17: conflict-free
    __shared__ float CGl[2 * 4 * 64 * 12];  // 24576 B, 48B rows, 16B-aligned

    const int tid  = threadIdx.x;
    const int lane = tid & 63;
    const int wv   = tid >> 6;

    // ---- phase-2 invariants (depend only on lane&31) ----
    const int jj  = lane & 31;         // float4-slot within an edge
    const int lm  = jj >> 1;           // 0..15
    const int k0  = (jj & 1) * 4;      // 0 or 4
    const int l   = (lm > 0) + (lm > 3) + (lm > 8);
    const f4  wl  = *reinterpret_cast<const f4*>(tw + l * NUM_RADIAL + k0);

    f4* out4 = reinterpret_cast<f4*>(out);
    const int stride = gridDim.x;

    auto loadA = [&](int T, float& dxo, float& dyo, float& dzo, int& zo) {
        const int e = T * TILE + wv * 64 + lane;
        if (e < n_edges) {
            dxo = disp[3 * e + 0];
            dyo = disp[3 * e + 1];
            dzo = disp[3 * e + 2];
            zo  = Zj[e];
        } else { dxo = 0.0f; dyo = 0.0f; dzo = 0.0f; zo = 0; }
    };

    auto compute = [&](int buf, float dx, float dy, float dz, f4 t0, f4 t1) {
        const float r2 = dx * dx + dy * dy + dz * dz;
        const float r  = sqrtf(r2);
        const float rinv = (r > 0.0f) ? __builtin_amdgcn_rcpf(r) : 0.0f;
        const float x = dx * rinv, y = dy * rinv, z = dz * rinv;
        const float x2 = x * x, y2 = y * y, z2 = z * z;

        const float s3   = 1.7320508075688772f;   // sqrt(3)
        const float s15  = 3.8729833462074170f;   // sqrt(15)
        const float s5_8 = 0.7905694150420949f;   // sqrt(5/8)
        const float s3_8 = 0.6123724356957945f;   // sqrt(3/8)

        float* Yp = &Yl[(buf * 4 + wv) * (64 * 17) + lane * 17];
        Yp[0]  = 1.0f;
        Yp[1]  = x;
        Yp[2]  = y;
        Yp[3]  = z;
        Yp[4]  = s3 * x * y;
        Yp[5]  = s3 * y * z;
        Yp[6]  = 0.5f * (3.0f * z2 - 1.0f);
        Yp[7]  = s3 * x * z;
        Yp[8]  = 0.5f * s3 * (x2 - y2);
        Yp[9]  = s5_8 * y * (3.0f * x2 - y2);
        Yp[10] = s15 * x * y * z;
        Yp[11] = s3_8 * y * (5.0f * z2 - 1.0f);
        Yp[12] = 0.5f * z * (5.0f * z2 - 3.0f);
        Yp[13] = s3_8 * x * (5.0f * z2 - 1.0f);
        Yp[14] = 0.5f * s15 * z * (x2 - y2);
        Yp[15] = s5_8 * x * (x2 - 3.0f * y2);

        const float PI  = 3.14159265358979323846f;
        const float cut = (r < 5.0f) ? (0.5f * (__cosf(PI * r * 0.2f) + 1.0f))
                                     : 0.0f;
        const float pib = PI * r * 0.2f;   // pi*r/CUTOFF

        float t[NUM_RADIAL] = { t0.x, t0.y, t0.z, t0.w, t1.x, t1.y, t1.z, t1.w };

        f4 cga, cgb;
        #pragma unroll
        for (int k = 0; k < NUM_RADIAL; ++k) {
            const float px = pib * (float)(k + 1);
            const float s  = (px != 0.0f) ? (__sinf(px) * __builtin_amdgcn_rcpf(px))
                                          : 1.0f;              // sinc
            const float c  = t[k] * (s * cut);
            const float y0 = c * tw[k];                         // w[0][k]
            const float gate = __builtin_amdgcn_rcpf(1.0f + __expf(-y0));
            const float cg = c * gate;
            if (k < 4) ((float*)&cga)[k] = cg; else ((float*)&cgb)[k - 4] = cg;
        }
        f4* CGp = reinterpret_cast<f4*>(
            &CGl[(buf * 4 + wv) * (64 * 12) + lane * 12]);
        CGp[0] = cga;
        CGp[1] = cgb;
    };

    auto stores = [&](int T, int buf) {
        const int ebase  = T * TILE + wv * 64;
        const int ybase  = (buf * 4 + wv) * (64 * 17);
        const int cgbase = (buf * 4 + wv) * (64 * 12);
        #pragma unroll 8
        for (int it = 0; it < 32; ++it) {
            const int el   = it * 2 + (lane >> 5);   // wave-local edge
            const int edge = ebase + el;
            if (edge < n_edges) {
                const float yv = Yl[ybase + el * 17 + lm];
                const f4 cg = *reinterpret_cast<const f4*>(&CGl[cgbase + el * 12 + k0]);
                out4[edge * 32 + jj] = (yv * cg) * wl;
            }
        }
    };

    // ---- pipeline prologue: tile T into buffer 0 ----
    int T = blockIdx.x;
    if (T >= ntiles) return;

    float dxA, dyA, dzA; int zA;
    loadA(T, dxA, dyA, dzA, zA);
    const f4 t0A = *reinterpret_cast<const f4*>(t_table + zA * NUM_RADIAL);
    const f4 t1A = *reinterpret_cast<const f4*>(t_table + zA * NUM_RADIAL + 4);

    int  Tn   = T + stride;
    bool more = (Tn < ntiles);
    float dxB = 0.0f, dyB = 0.0f, dzB = 0.0f; int zB = 0;
    if (more) loadA(Tn, dxB, dyB, dzB, zB);   // in flight across compute

    compute(0, dxA, dyA, dzA, t0A, t1A);
    __asm__ volatile("s_waitcnt lgkmcnt(0)" ::: "memory");
    __builtin_amdgcn_sched_barrier(0);

    // ---- steady state ----
    int cur = 0;
    while (more) {
        const int  T2    = Tn + stride;
        const bool more2 = (T2 < ntiles);
        float dxC = 0.0f, dyC = 0.0f, dzC = 0.0f; int zC = 0;
        if (more2) loadA(T2, dxC, dyC, dzC, zC);        // issue early
        const f4 t0B = *reinterpret_cast<const f4*>(t_table + zB * NUM_RADIAL);
        const f4 t1B = *reinterpret_cast<const f4*>(t_table + zB * NUM_RADIAL + 4);

        stores(T, cur);                                  // 32 KB drain hides latency

        compute(cur ^ 1, dxB, dyB, dzB, t0B, t1B);
        __asm__ volatile("s_waitcnt lgkmcnt(0)" ::: "memory");
        __builtin_amdgcn_sched_barrier(0);

        T = Tn; Tn = T2;
        dxB = dxC; dyB = dyC; dzB = dzC; zB = zC;
        more = more2;
        cur ^= 1;
    }

    stores(T, cur);   // drain final tile
}

extern "C" void kernel_launch(void* const* d_in, const int* in_sizes, int n_in,
                              void* d_out, int out_size, void* d_ws, size_t ws_size,
                              hipStream_t stream) {
    const float* disp = (const float*)d_in[0];
    const int*   Zj   = (const int*)  d_in[1];
    const float* emb  = (const float*)d_in[2];
    const float* dw   = (const float*)d_in[3];
    const float* db   = (const float*)d_in[4];
    const float* tw   = (const float*)d_in[5];
    float* t_table = (float*)d_ws;                    // 83*8 floats = 2656 B
    float* out     = (float*)d_out;

    const int n = in_sizes[1];                        // N_EDGES

    hipLaunchKernelGGL(srb_precompute_t, dim3(3), dim3(256), 0, stream,
                       emb, dw, db, t_table);

    const int ntiles = (n + TILE - 1) / TILE;
    const int nb = (ntiles < NBLOCKS) ? ntiles : NBLOCKS;
    hipLaunchKernelGGL(srb_main, dim3(nb), dim3(256), 0, stream,
                       disp, Zj, tw, t_table, out, n, ntiles);
}

// Round 9
// 42.171 us; speedup vs baseline: 1.0413x; 1.0192x over previous
//
#include <hip/hip_runtime.h>
#include <math.h>

#define NUM_RADIAL 8
#define EMB_DIM    64
#define N_ELEM     83
#define TILE       256   // edges per block; each wave owns 64 edges

typedef float f4 __attribute__((ext_vector_type(4)));

// ---------------------------------------------------------------------------
// Kernel 1: t_table[z][k] = emb_table[z] . dense_w[:,k] + dense_b[k]
// ---------------------------------------------------------------------------
__global__ void srb_precompute_t(const float* __restrict__ emb,
                                 const float* __restrict__ dw,
                                 const float* __restrict__ db,
                                 float* __restrict__ t_table) {
    int idx = blockIdx.x * blockDim.x + threadIdx.x;
    if (idx >= N_ELEM * NUM_RADIAL) return;
    int z = idx >> 3;
    int k = idx & 7;
    float acc = db[k];
    const float* e = emb + z * EMB_DIM;
    #pragma unroll 8
    for (int j = 0; j < EMB_DIM; ++j)
        acc += e[j] * dw[j * NUM_RADIAL + k];
    t_table[idx] = acc;
}

// ---------------------------------------------------------------------------
// Kernel 2: main edge kernel — wave-synchronous, NO __syncthreads.
// Each wave owns a 64-edge segment. Phase 1: lane i computes edge i's Y[16]
// (LDS stride 17) and gated radial cg[8] (LDS stride 12, 48B rows). Phase 2:
// after a wave-local s_waitcnt lgkmcnt(0), the same wave re-maps lanes so one
// wave-instruction stores 1KB contiguous (2 edges x 512B) per iteration.
// out[e][lm][k] = Y[lm] * cg[k] * w[deg(lm)][k]; each thread's (lm,k0,deg)
// is fixed => its w[deg][k0..3] float4 stays in registers.
// Waves never wait on each other -> independent store streams.
// ---------------------------------------------------------------------------
__global__ __launch_bounds__(256) void srb_main(
    const float* __restrict__ disp,
    const int*   __restrict__ Zj,
    const float* __restrict__ tw,       // tensor_w, 4 x 8
    const float* __restrict__ t_table,  // 83 x 8
    float*       __restrict__ out,
    int n_edges)
{
    __shared__ float Yl[TILE * 17];    // stride 17 (odd): conflict-free b32
    __shared__ float CGl[TILE * 12];   // stride 12 floats = 48B, 16B-aligned

    const int tid  = threadIdx.x;
    const int lane = tid & 63;
    const int wv   = tid >> 6;
    const int e    = blockIdx.x * TILE + tid;

    // ---- phase-2 invariants (depend only on lane&31) ----
    const int jj  = lane & 31;         // float4-slot within an edge
    const int lm  = jj >> 1;           // 0..15
    const int k0  = (jj & 1) * 4;      // 0 or 4
    const int l   = (lm > 0) + (lm > 3) + (lm > 8);
    const f4  wl  = *reinterpret_cast<const f4*>(tw + l * NUM_RADIAL + k0);

    if (e < n_edges) {
        const float dx = disp[3 * e + 0];
        const float dy = disp[3 * e + 1];
        const float dz = disp[3 * e + 2];
        const float r2 = dx * dx + dy * dy + dz * dz;
        const float r  = sqrtf(r2);
        const float rinv = (r > 0.0f) ? __builtin_amdgcn_rcpf(r) : 0.0f;
        const float x = dx * rinv, y = dy * rinv, z = dz * rinv;
        const float x2 = x * x, y2 = y * y, z2 = z * z;

        const float s3   = 1.7320508075688772f;   // sqrt(3)
        const float s15  = 3.8729833462074170f;   // sqrt(15)
        const float s5_8 = 0.7905694150420949f;   // sqrt(5/8)
        const float s3_8 = 0.6123724356957945f;   // sqrt(3/8)

        float* Yp = &Yl[tid * 17];
        Yp[0]  = 1.0f;
        Yp[1]  = x;
        Yp[2]  = y;
        Yp[3]  = z;
        Yp[4]  = s3 * x * y;
        Yp[5]  = s3 * y * z;
        Yp[6]  = 0.5f * (3.0f * z2 - 1.0f);
        Yp[7]  = s3 * x * z;
        Yp[8]  = 0.5f * s3 * (x2 - y2);
        Yp[9]  = s5_8 * y * (3.0f * x2 - y2);
        Yp[10] = s15 * x * y * z;
        Yp[11] = s3_8 * y * (5.0f * z2 - 1.0f);
        Yp[12] = 0.5f * z * (5.0f * z2 - 3.0f);
        Yp[13] = s3_8 * x * (5.0f * z2 - 1.0f);
        Yp[14] = 0.5f * s15 * z * (x2 - y2);
        Yp[15] = s5_8 * x * (x2 - 3.0f * y2);

        const float PI  = 3.14159265358979323846f;
        const float cut = (r < 5.0f) ? (0.5f * (__cosf(PI * r * 0.2f) + 1.0f))
                                     : 0.0f;
        const float pib = PI * r * 0.2f;   // pi*r/CUTOFF

        const int zidx = Zj[e];
        const f4 t0 = *reinterpret_cast<const f4*>(t_table + zidx * NUM_RADIAL);
        const f4 t1 = *reinterpret_cast<const f4*>(t_table + zidx * NUM_RADIAL + 4);
        float t[NUM_RADIAL] = { t0.x, t0.y, t0.z, t0.w, t1.x, t1.y, t1.z, t1.w };

        f4 cga, cgb;
        #pragma unroll
        for (int k = 0; k < NUM_RADIAL; ++k) {
            const float px = pib * (float)(k + 1);
            const float s  = (px != 0.0f) ? (__sinf(px) * __builtin_amdgcn_rcpf(px))
                                          : 1.0f;              // sinc
            const float c  = t[k] * (s * cut);
            const float y0 = c * tw[k];                         // w[0][k]
            const float gate = __builtin_amdgcn_rcpf(1.0f + __expf(-y0));
            const float cg = c * gate;
            if (k < 4) ((float*)&cga)[k] = cg; else ((float*)&cgb)[k - 4] = cg;
        }
        f4* CGp = reinterpret_cast<f4*>(&CGl[tid * 12]);
        CGp[0] = cga;
        CGp[1] = cgb;
    }

    // Wave-local phase boundary: drain this wave's LDS writes, pin ordering.
    __asm__ volatile("s_waitcnt lgkmcnt(0)" ::: "memory");
    __builtin_amdgcn_sched_barrier(0);

    // Phase 2: this wave streams its own 64 edges (2 edges / wave-inst,
    // 1KB contiguous per wave-instruction).
    const int el0 = wv * 64;
    f4* out4 = reinterpret_cast<f4*>(out);
    #pragma unroll 8
    for (int it = 0; it < 32; ++it) {
        const int el   = el0 + it * 2 + (lane >> 5);   // local edge
        const int edge = blockIdx.x * TILE + el;
        if (edge < n_edges) {
            const float yv = Yl[el * 17 + lm];
            const f4 cg = *reinterpret_cast<const f4*>(&CGl[el * 12 + k0]);
            const f4 o  = (yv * cg) * wl;
            out4[edge * 32 + jj] = o;
        }
    }
}

extern "C" void kernel_launch(void* const* d_in, const int* in_sizes, int n_in,
                              void* d_out, int out_size, void* d_ws, size_t ws_size,
                              hipStream_t stream) {
    const float* disp = (const float*)d_in[0];
    const int*   Zj   = (const int*)  d_in[1];
    const float* emb  = (const float*)d_in[2];
    const float* dw   = (const float*)d_in[3];
    const float* db   = (const float*)d_in[4];
    const float* tw   = (const float*)d_in[5];
    float* t_table = (float*)d_ws;                    // 83*8 floats = 2656 B
    float* out     = (float*)d_out;

    const int n = in_sizes[1];                        // N_EDGES

    hipLaunchKernelGGL(srb_precompute_t, dim3(3), dim3(256), 0, stream,
                       emb, dw, db, t_table);

    const int nblocks = (n + TILE - 1) / TILE;
    hipLaunchKernelGGL(srb_main, dim3(nblocks), dim3(256), 0, stream,
                       disp, Zj, tw, t_table, out, n);
}